// Round 3
// baseline (911.905 us; speedup 1.0000x reference)
//
#include <hip/hip_runtime.h>

// GNN_22505628631761: 2-layer GCN (sym-norm, self-loops) + residual + 3 outputs.
// R3: inputs/outputs are FLOAT32 (per the reference) — R1/R2 read them as bf16,
//     which mints NaNs (fp32 mantissa bits decode as bf16 exponents). Internals:
//     bf16 MFMA GEMMs (RNE-converted), bf16 h buffers to halve gather traffic,
//     fp32 accumulate + fp32 outputs.

typedef __attribute__((ext_vector_type(8))) short bf16x8;
typedef __attribute__((ext_vector_type(4))) float f32x4;

#define CDIV(a, b) (((a) + (b) - 1) / (b))

__device__ __forceinline__ float b2f(unsigned short u) {
  union { unsigned int i; float f; } x; x.i = ((unsigned int)u) << 16; return x.f;
}
__device__ __forceinline__ unsigned short f2b(float f) {
  union { float f; unsigned int i; } x; x.f = f;
  unsigned int r = x.i + 0x7fffu + ((x.i >> 16) & 1u);  // RNE
  return (unsigned short)(r >> 16);
}

// ---------------- setup kernels ----------------

// W [K][N] fp32 -> Wt [N][K] bf16
__global__ void k_wtrans(const float* __restrict__ in,
                         unsigned short* __restrict__ out, int K, int N) {
  int idx = blockIdx.x * blockDim.x + threadIdx.x;
  if (idx >= K * N) return;
  int k = idx / N, n = idx - k * N;
  out[n * K + k] = f2b(in[idx]);
}

__global__ void k_degcount(const int* __restrict__ ei, int E, int* __restrict__ deg) {
  int e = blockIdx.x * blockDim.x + threadIdx.x;
  if (e >= E) return;
  atomicAdd(&deg[ei[E + e]], 1);
}

__global__ void k_dinv(const int* __restrict__ deg, float* __restrict__ dinv, int n) {
  int i = blockIdx.x * blockDim.x + threadIdx.x;
  if (i >= n) return;
  dinv[i] = 1.0f / sqrtf((float)deg[i] + 1.0f);  // self-loop => deg >= 1
}

// 3-phase exclusive scan over deg (2048 elems/block); local scan -> row_start
__global__ void k_scan1(const int* __restrict__ deg, int* __restrict__ lscan,
                        int* __restrict__ partials, int n) {
  __shared__ int sd[256];
  int tid = threadIdx.x;
  int base = blockIdx.x * 2048 + tid * 8;
  int v[8]; int tsum = 0;
#pragma unroll
  for (int i = 0; i < 8; ++i) {
    int idx = base + i;
    int xv = (idx < n) ? deg[idx] : 0;
    v[i] = xv; tsum += xv;
  }
  sd[tid] = tsum;
  __syncthreads();
  for (int off = 1; off < 256; off <<= 1) {
    int t = (tid >= off) ? sd[tid - off] : 0;
    __syncthreads();
    sd[tid] += t;
    __syncthreads();
  }
  int run = sd[tid] - tsum;
#pragma unroll
  for (int i = 0; i < 8; ++i) {
    int idx = base + i;
    if (idx < n) lscan[idx] = run;
    run += v[i];
  }
  if (tid == 255) partials[blockIdx.x] = sd[255];
}

__global__ void k_scan2(const int* __restrict__ partials, int* __restrict__ pprefix, int nb) {
  if (threadIdx.x == 0 && blockIdx.x == 0) {
    int run = 0;
    for (int i = 0; i < nb; ++i) { pprefix[i] = run; run += partials[i]; }
    pprefix[nb] = run;
  }
}

__global__ void k_scan3(const int* __restrict__ pprefix, int* row_start,
                        int* __restrict__ cursor, int n, int E) {
  int idx = blockIdx.x * blockDim.x + threadIdx.x;
  if (idx >= n) return;
  int v = row_start[idx] + pprefix[idx >> 11];
  row_start[idx] = v;
  cursor[idx] = v;
  if (idx == 0) row_start[n] = E;
}

__global__ void k_scatter(const int* __restrict__ ei, int E, int* __restrict__ cursor,
                          int* __restrict__ csr_src) {
  int e = blockIdx.x * blockDim.x + threadIdx.x;
  if (e >= E) return;
  int s = ei[e], d = ei[E + e];
  int pos = atomicAdd(&cursor[d], 1);
  csr_src[pos] = s;
}

// ---------------- GEMMs (MFMA bf16 16x16x32, fp32 A converted on the fly) ----
// Block = 4 waves x 16 rows = 64-row tile, 128 output cols per wave.
// A frag: lane holds A[m=lane&15][k=(lane>>4)*8+j]; B frag from Bt[n][k] likewise.
// C/D: col = lane&15, row = (lane>>4)*4 + reg.

__device__ __forceinline__ bf16x8 load_a_f32(const float* p) {
  const float4* a4 = (const float4*)p;
  float4 lo = a4[0], hi = a4[1];
  bf16x8 a;
  a[0] = (short)f2b(lo.x); a[1] = (short)f2b(lo.y);
  a[2] = (short)f2b(lo.z); a[3] = (short)f2b(lo.w);
  a[4] = (short)f2b(hi.x); a[5] = (short)f2b(hi.y);
  a[6] = (short)f2b(hi.z); a[7] = (short)f2b(hi.w);
  return a;
}

// x@W1 -> O1 (bf16) and x@Wd+bd -> O2 (fp32, residual), reading x once
__global__ __launch_bounds__(256) void k_gemm_x2(
    const float* __restrict__ X,             // [n,256] fp32
    const unsigned short* __restrict__ B1t,  // [128,256] bf16 = W1^T
    const unsigned short* __restrict__ B2t,  // [128,256] bf16 = Wd^T
    const float* __restrict__ bias2,         // bd [128] fp32
    unsigned short* __restrict__ O1, float* __restrict__ O2, int n) {
  int wave = threadIdx.x >> 6, lane = threadIdx.x & 63;
  int l15 = lane & 15, q = lane >> 4;
  int rowA = blockIdx.x * 64 + wave * 16 + l15;
  if (rowA >= n) rowA = n - 1;  // clamp (stores are guarded)
  f32x4 acc1[8], acc2[8];
#pragma unroll
  for (int i = 0; i < 8; ++i) {
    acc1[i] = (f32x4){0.f, 0.f, 0.f, 0.f};
    acc2[i] = (f32x4){0.f, 0.f, 0.f, 0.f};
  }
  const float* ap = X + (size_t)rowA * 256 + q * 8;
#pragma unroll
  for (int kb = 0; kb < 8; ++kb) {
    bf16x8 a = load_a_f32(ap + kb * 32);
#pragma unroll
    for (int nt = 0; nt < 8; ++nt) {
      bf16x8 bv1 = *(const bf16x8*)(B1t + (nt * 16 + l15) * 256 + kb * 32 + q * 8);
      acc1[nt] = __builtin_amdgcn_mfma_f32_16x16x32_bf16(a, bv1, acc1[nt], 0, 0, 0);
      bf16x8 bv2 = *(const bf16x8*)(B2t + (nt * 16 + l15) * 256 + kb * 32 + q * 8);
      acc2[nt] = __builtin_amdgcn_mfma_f32_16x16x32_bf16(a, bv2, acc2[nt], 0, 0, 0);
    }
  }
  int rowBase = blockIdx.x * 64 + wave * 16 + q * 4;
#pragma unroll
  for (int nt = 0; nt < 8; ++nt) {
    int col = nt * 16 + l15;
    float bb = bias2[col];
#pragma unroll
    for (int r = 0; r < 4; ++r) {
      int row = rowBase + r;
      if (row < n) {
        O1[(size_t)row * 128 + col] = f2b(acc1[nt][r]);
        O2[(size_t)row * 128 + col] = acc2[nt][r] + bb;
      }
    }
  }
}

// A bf16 [n,128] @ Bt bf16 -> O bf16 (h1@W2)
__global__ __launch_bounds__(256) void k_gemm_h_b16(
    const unsigned short* __restrict__ X, const unsigned short* __restrict__ Bt,
    unsigned short* __restrict__ O, int n) {
  int wave = threadIdx.x >> 6, lane = threadIdx.x & 63;
  int l15 = lane & 15, q = lane >> 4;
  int rowA = blockIdx.x * 64 + wave * 16 + l15;
  if (rowA >= n) rowA = n - 1;
  f32x4 acc[8];
#pragma unroll
  for (int i = 0; i < 8; ++i) acc[i] = (f32x4){0.f, 0.f, 0.f, 0.f};
  const unsigned short* ap = X + (size_t)rowA * 128 + q * 8;
#pragma unroll
  for (int kb = 0; kb < 4; ++kb) {
    bf16x8 a = *(const bf16x8*)(ap + kb * 32);
#pragma unroll
    for (int nt = 0; nt < 8; ++nt) {
      bf16x8 bv = *(const bf16x8*)(Bt + (nt * 16 + l15) * 128 + kb * 32 + q * 8);
      acc[nt] = __builtin_amdgcn_mfma_f32_16x16x32_bf16(a, bv, acc[nt], 0, 0, 0);
    }
  }
  int rowBase = blockIdx.x * 64 + wave * 16 + q * 4;
#pragma unroll
  for (int nt = 0; nt < 8; ++nt) {
    int col = nt * 16 + l15;
#pragma unroll
    for (int r = 0; r < 4; ++r) {
      int row = rowBase + r;
      if (row < n) O[(size_t)row * 128 + col] = f2b(acc[nt][r]);
    }
  }
}

// A bf16 [n,128] @ Bt bf16 + bias -> O fp32 (final h@W3+b3)
__global__ __launch_bounds__(256) void k_gemm_h_f32(
    const unsigned short* __restrict__ X, const unsigned short* __restrict__ Bt,
    const float* __restrict__ bias, float* __restrict__ O, int n) {
  int wave = threadIdx.x >> 6, lane = threadIdx.x & 63;
  int l15 = lane & 15, q = lane >> 4;
  int rowA = blockIdx.x * 64 + wave * 16 + l15;
  if (rowA >= n) rowA = n - 1;
  f32x4 acc[8];
#pragma unroll
  for (int i = 0; i < 8; ++i) acc[i] = (f32x4){0.f, 0.f, 0.f, 0.f};
  const unsigned short* ap = X + (size_t)rowA * 128 + q * 8;
#pragma unroll
  for (int kb = 0; kb < 4; ++kb) {
    bf16x8 a = *(const bf16x8*)(ap + kb * 32);
#pragma unroll
    for (int nt = 0; nt < 8; ++nt) {
      bf16x8 bv = *(const bf16x8*)(Bt + (nt * 16 + l15) * 128 + kb * 32 + q * 8);
      acc[nt] = __builtin_amdgcn_mfma_f32_16x16x32_bf16(a, bv, acc[nt], 0, 0, 0);
    }
  }
  int rowBase = blockIdx.x * 64 + wave * 16 + q * 4;
#pragma unroll
  for (int nt = 0; nt < 8; ++nt) {
    int col = nt * 16 + l15;
    float bb = bias[col];
#pragma unroll
    for (int r = 0; r < 4; ++r) {
      int row = rowBase + r;
      if (row < n) O[(size_t)row * 128 + col] = acc[nt][r] + bb;
    }
  }
}

// ---------------- aggregation (wave per node, 2 feats/lane) ----------------

__global__ __launch_bounds__(256) void k_agg1(
    const unsigned short* __restrict__ h,   // xW1 bf16 [n,128]
    const int* __restrict__ row_start, const int* __restrict__ csr_src,
    const float* __restrict__ dinv,
    const float* __restrict__ bias,         // b1 fp32
    unsigned short* __restrict__ hout, int n) {
  int gw = blockIdx.x * (blockDim.x >> 6) + (threadIdx.x >> 6);
  int lane = threadIdx.x & 63;
  if (gw >= n) return;
  int beg = row_start[gw], end = row_start[gw + 1];
  float dg = dinv[gw];
  float a0 = 0.f, a1 = 0.f;
  for (int e = beg; e < end; ++e) {
    int s = csr_src[e];
    if ((unsigned)s >= (unsigned)n) continue;  // diagnostic guard
    float c = dinv[s];
    unsigned int v = *(const unsigned int*)(h + (size_t)s * 128 + lane * 2);
    a0 += c * b2f((unsigned short)v);
    a1 += c * b2f((unsigned short)(v >> 16));
  }
  a0 *= dg; a1 *= dg;  // coef = dinv[s]*dinv[gw]
  float sc = dg * dg;
  unsigned int v = *(const unsigned int*)(h + (size_t)gw * 128 + lane * 2);
  a0 += sc * b2f((unsigned short)v);
  a1 += sc * b2f((unsigned short)(v >> 16));
  a0 += bias[lane * 2];
  a1 += bias[lane * 2 + 1];
  a0 = fmaxf(a0, 0.f);  // relu
  a1 = fmaxf(a1, 0.f);
  unsigned int o = (unsigned int)f2b(a0) | ((unsigned int)f2b(a1) << 16);
  *(unsigned int*)(hout + (size_t)gw * 128 + lane * 2) = o;
}

// layer-2 aggregation + residual + b2 -> h; then log_softmax (out1, in place over
// the residual row), Wdeg head (out2), and bf16 h copy for the W3 GEMM.
// res_out1 row gw is read then written by the SAME wave only — safe aliasing.
__global__ __launch_bounds__(256) void k_agg2_epi(
    const unsigned short* __restrict__ h,   // h1@W2 bf16 [n,128]
    const int* __restrict__ row_start, const int* __restrict__ csr_src,
    const float* __restrict__ dinv,
    const float* __restrict__ bias,    // b2 fp32
    float* res_out1,                   // in: x@Wd+bd (fp32); out: log_softmax
    const float* __restrict__ wdeg,    // [128]
    const float* __restrict__ bdeg,    // [1]
    float* __restrict__ out2,          // [n]
    unsigned short* __restrict__ hf,   // h bf16 [n,128]
    int n) {
  int gw = blockIdx.x * (blockDim.x >> 6) + (threadIdx.x >> 6);
  int lane = threadIdx.x & 63;
  if (gw >= n) return;
  int beg = row_start[gw], end = row_start[gw + 1];
  float dg = dinv[gw];
  float a0 = 0.f, a1 = 0.f;
  for (int e = beg; e < end; ++e) {
    int s = csr_src[e];
    if ((unsigned)s >= (unsigned)n) continue;
    float c = dinv[s];
    unsigned int v = *(const unsigned int*)(h + (size_t)s * 128 + lane * 2);
    a0 += c * b2f((unsigned short)v);
    a1 += c * b2f((unsigned short)(v >> 16));
  }
  a0 *= dg; a1 *= dg;
  float sc = dg * dg;
  unsigned int v = *(const unsigned int*)(h + (size_t)gw * 128 + lane * 2);
  a0 += sc * b2f((unsigned short)v);
  a1 += sc * b2f((unsigned short)(v >> 16));
  a0 += bias[lane * 2];
  a1 += bias[lane * 2 + 1];
  float2 rv = *(const float2*)(res_out1 + (size_t)gw * 128 + lane * 2);
  a0 += rv.x;
  a1 += rv.y;
  // bf16 h copy for W3 GEMM
  unsigned int o = (unsigned int)f2b(a0) | ((unsigned int)f2b(a1) << 16);
  *(unsigned int*)(hf + (size_t)gw * 128 + lane * 2) = o;
  // result2 = h . Wdeg + bdeg
  float t = a0 * wdeg[lane * 2] + a1 * wdeg[lane * 2 + 1];
#pragma unroll
  for (int m = 32; m >= 1; m >>= 1) t += __shfl_xor(t, m);
  if (lane == 0) out2[gw] = t + bdeg[0];
  // log_softmax over 128 feats
  float mx = fmaxf(a0, a1);
#pragma unroll
  for (int m = 32; m >= 1; m >>= 1) mx = fmaxf(mx, __shfl_xor(mx, m));
  float l = __expf(a0 - mx) + __expf(a1 - mx);
#pragma unroll
  for (int m = 32; m >= 1; m >>= 1) l += __shfl_xor(l, m);
  float ls = mx + __logf(l);
  float2 o1; o1.x = a0 - ls; o1.y = a1 - ls;
  *(float2*)(res_out1 + (size_t)gw * 128 + lane * 2) = o1;
}

// ---------------- launch ----------------

extern "C" void kernel_launch(void* const* d_in, const int* in_sizes, int n_in,
                              void* d_out, int out_size, void* d_ws, size_t ws_size,
                              hipStream_t stream) {
  const float* x   = (const float*)d_in[0];
  const int*   ei  = (const int*)d_in[1];
  const float* W1  = (const float*)d_in[2];
  const float* b1  = (const float*)d_in[3];
  const float* W2  = (const float*)d_in[4];
  const float* b2  = (const float*)d_in[5];
  const float* Wd  = (const float*)d_in[6];
  const float* bd  = (const float*)d_in[7];
  const float* Wdg = (const float*)d_in[8];
  const float* bdg = (const float*)d_in[9];
  const float* W3  = (const float*)d_in[10];
  const float* b3  = (const float*)d_in[11];

  const int N = in_sizes[0] / 256;
  const int E = in_sizes[1] / 2;

  // ---- workspace layout (~34 MB) ----
  char* w = (char*)d_ws;
  auto alloc = [&](size_t bytes) {
    char* p = w;
    w += (bytes + 255) & ~(size_t)255;
    return p;
  };
  unsigned short* W1t  = (unsigned short*)alloc((size_t)256 * 128 * 2);
  unsigned short* Wdt  = (unsigned short*)alloc((size_t)256 * 128 * 2);
  unsigned short* W2t  = (unsigned short*)alloc((size_t)128 * 128 * 2);
  unsigned short* W3t  = (unsigned short*)alloc((size_t)128 * 128 * 2);
  unsigned short* bufC = (unsigned short*)alloc((size_t)N * 128 * 2);  // h1 / h_final bf16
  int*   deg      = (int*)alloc((size_t)N * 4);
  float* dinv     = (float*)alloc((size_t)N * 4);
  int*   row_start= (int*)alloc((size_t)(N + 1) * 4);
  int*   cursor   = (int*)alloc((size_t)N * 4);
  int*   partials = (int*)alloc(4096);
  int*   pprefix  = (int*)alloc(4096);
  int*   csr_src  = (int*)alloc((size_t)E * 4);

  // ---- d_out (fp32) regions; out3 region doubles as bf16 scratch bufA ----
  float* out1 = (float*)d_out;               // [N,128] log_softmax; holds residual first
  float* out2 = out1 + (size_t)N * 128;      // [N]
  float* out3 = out2 + (size_t)N;            // [N,128] result3
  unsigned short* bufA = (unsigned short*)out3;  // xW1 / h1W2 bf16 (dead before out3 write)

  hipMemsetAsync(deg, 0, (size_t)N * 4, stream);

  k_wtrans<<<CDIV(256 * 128, 256), 256, 0, stream>>>(W1, W1t, 256, 128);
  k_wtrans<<<CDIV(256 * 128, 256), 256, 0, stream>>>(Wd, Wdt, 256, 128);
  k_wtrans<<<CDIV(128 * 128, 256), 256, 0, stream>>>(W2, W2t, 128, 128);
  k_wtrans<<<CDIV(128 * 128, 256), 256, 0, stream>>>(W3, W3t, 128, 128);

  k_degcount<<<CDIV(E, 256), 256, 0, stream>>>(ei, E, deg);

  // fused x@W1 -> bufA (bf16) and x@Wd+bd -> out1 (fp32 residual)
  k_gemm_x2<<<CDIV(N, 64), 256, 0, stream>>>(x, W1t, Wdt, bd, bufA, out1, N);

  k_dinv<<<CDIV(N, 256), 256, 0, stream>>>(deg, dinv, N);

  const int nb = CDIV(N, 2048);
  k_scan1<<<nb, 256, 0, stream>>>(deg, row_start, partials, N);
  k_scan2<<<1, 64, 0, stream>>>(partials, pprefix, nb);
  k_scan3<<<CDIV(N, 256), 256, 0, stream>>>(pprefix, row_start, cursor, N, E);
  k_scatter<<<CDIV(E, 256), 256, 0, stream>>>(ei, E, cursor, csr_src);

  // GCN layer 1: aggregate xW1, +b1, relu -> h1 (bufC, bf16)
  k_agg1<<<CDIV(N, 4), 256, 0, stream>>>(bufA, row_start, csr_src, dinv, b1, bufC, N);

  // h1 @ W2 -> bufA (bf16)
  k_gemm_h_b16<<<CDIV(N, 64), 256, 0, stream>>>(bufC, W2t, bufA, N);

  // layer-2 aggregate + b2 + residual; log_softmax -> out1, deg-head -> out2,
  // h (bf16) -> bufC
  k_agg2_epi<<<CDIV(N, 4), 256, 0, stream>>>(bufA, row_start, csr_src, dinv,
                                             b2, out1, Wdg, bdg, out2, bufC, N);

  // result3 = h @ W3 + b3 -> out3 (fp32; overwrites dead bufA)
  k_gemm_h_f32<<<CDIV(N, 64), 256, 0, stream>>>(bufC, W3t, b3, out3, N);
}

// Round 4
// 707.586 us; speedup vs baseline: 1.2888x; 1.2888x over previous
//
#include <hip/hip_runtime.h>

// GNN_22505628631761: 2-layer GCN (sym-norm, self-loops) + residual + 3 outputs.
// fp32 in/out; bf16 MFMA GEMMs + bf16 h buffers internally.
// R4: aggregation loops restructured for MLP — 64 edge indices+coefs batch-loaded
//     per wave, readlane broadcast, 4 row-gathers in flight (R3 was latency-bound:
//     VALUBusy 27%, HBM 21%, serial per-edge chain). dinv folded into scan1,
//     weight transposes fused into one launch.

typedef __attribute__((ext_vector_type(8))) short bf16x8;
typedef __attribute__((ext_vector_type(4))) float f32x4;

#define CDIV(a, b) (((a) + (b) - 1) / (b))

__device__ __forceinline__ float b2f(unsigned short u) {
  union { unsigned int i; float f; } x; x.i = ((unsigned int)u) << 16; return x.f;
}
__device__ __forceinline__ unsigned short f2b(float f) {
  union { float f; unsigned int i; } x; x.f = f;
  unsigned int r = x.i + 0x7fffu + ((x.i >> 16) & 1u);  // RNE
  return (unsigned short)(r >> 16);
}
__device__ __forceinline__ float rlf(float v, int j) {
  union { float f; int i; } x; x.f = v;
  x.i = __builtin_amdgcn_readlane(x.i, j);
  return x.f;
}

// ---------------- setup kernels ----------------

// all four W [K][N] fp32 -> Wt [N][K] bf16 in one launch
__global__ void k_wtrans4(const float* __restrict__ W1, const float* __restrict__ Wd,
                          const float* __restrict__ W2, const float* __restrict__ W3,
                          unsigned short* __restrict__ W1t, unsigned short* __restrict__ Wdt,
                          unsigned short* __restrict__ W2t, unsigned short* __restrict__ W3t) {
  int idx = blockIdx.x * blockDim.x + threadIdx.x;
  const float* in; unsigned short* out; int K, N;
  if (idx < 32768)       { in = W1; out = W1t; K = 256; N = 128; }
  else if (idx < 65536)  { in = Wd; out = Wdt; K = 256; N = 128; idx -= 32768; }
  else if (idx < 81920)  { in = W2; out = W2t; K = 128; N = 128; idx -= 65536; }
  else if (idx < 98304)  { in = W3; out = W3t; K = 128; N = 128; idx -= 81920; }
  else return;
  int k = idx / N, n = idx - k * N;
  out[n * K + k] = f2b(in[idx]);
}

__global__ void k_degcount(const int* __restrict__ ei, int E, int* __restrict__ deg) {
  int e = blockIdx.x * blockDim.x + threadIdx.x;
  if (e >= E) return;
  atomicAdd(&deg[ei[E + e]], 1);
}

// exclusive scan over deg (2048/block) + dinv = rsqrt(deg+1)
__global__ void k_scan1(const int* __restrict__ deg, int* __restrict__ lscan,
                        int* __restrict__ partials, float* __restrict__ dinv, int n) {
  __shared__ int sd[256];
  int tid = threadIdx.x;
  int base = blockIdx.x * 2048 + tid * 8;
  int v[8]; int tsum = 0;
#pragma unroll
  for (int i = 0; i < 8; ++i) {
    int idx = base + i;
    int xv = (idx < n) ? deg[idx] : 0;
    v[i] = xv; tsum += xv;
    if (idx < n) dinv[idx] = 1.0f / sqrtf((float)xv + 1.0f);
  }
  sd[tid] = tsum;
  __syncthreads();
  for (int off = 1; off < 256; off <<= 1) {
    int t = (tid >= off) ? sd[tid - off] : 0;
    __syncthreads();
    sd[tid] += t;
    __syncthreads();
  }
  int run = sd[tid] - tsum;
#pragma unroll
  for (int i = 0; i < 8; ++i) {
    int idx = base + i;
    if (idx < n) lscan[idx] = run;
    run += v[i];
  }
  if (tid == 255) partials[blockIdx.x] = sd[255];
}

__global__ void k_scan2(const int* __restrict__ partials, int* __restrict__ pprefix, int nb) {
  if (threadIdx.x == 0 && blockIdx.x == 0) {
    int run = 0;
    for (int i = 0; i < nb; ++i) { pprefix[i] = run; run += partials[i]; }
    pprefix[nb] = run;
  }
}

__global__ void k_scan3(const int* __restrict__ pprefix, int* row_start,
                        int* __restrict__ cursor, int n, int E) {
  int idx = blockIdx.x * blockDim.x + threadIdx.x;
  if (idx >= n) return;
  int v = row_start[idx] + pprefix[idx >> 11];
  row_start[idx] = v;
  cursor[idx] = v;
  if (idx == 0) row_start[n] = E;
}

__global__ void k_scatter(const int* __restrict__ ei, int E, int* __restrict__ cursor,
                          int* __restrict__ csr_src) {
  int e = blockIdx.x * blockDim.x + threadIdx.x;
  if (e >= E) return;
  int s = ei[e], d = ei[E + e];
  int pos = atomicAdd(&cursor[d], 1);
  csr_src[pos] = s;
}

// ---------------- GEMMs (MFMA bf16 16x16x32) ----------------
// Block = 4 waves x 16 rows; A frag lane: A[m=lane&15][k=(lane>>4)*8+j];
// B frag from Bt[n][k] same addressing; C/D: col=lane&15, row=(lane>>4)*4+reg.

__device__ __forceinline__ bf16x8 load_a_f32(const float* p) {
  const float4* a4 = (const float4*)p;
  float4 lo = a4[0], hi = a4[1];
  bf16x8 a;
  a[0] = (short)f2b(lo.x); a[1] = (short)f2b(lo.y);
  a[2] = (short)f2b(lo.z); a[3] = (short)f2b(lo.w);
  a[4] = (short)f2b(hi.x); a[5] = (short)f2b(hi.y);
  a[6] = (short)f2b(hi.z); a[7] = (short)f2b(hi.w);
  return a;
}

__global__ __launch_bounds__(256) void k_gemm_x2(
    const float* __restrict__ X,             // [n,256] fp32
    const unsigned short* __restrict__ B1t,  // [128,256] bf16 = W1^T
    const unsigned short* __restrict__ B2t,  // [128,256] bf16 = Wd^T
    const float* __restrict__ bias2,         // bd
    unsigned short* __restrict__ O1, float* __restrict__ O2, int n) {
  int wave = threadIdx.x >> 6, lane = threadIdx.x & 63;
  int l15 = lane & 15, q = lane >> 4;
  int rowA = blockIdx.x * 64 + wave * 16 + l15;
  if (rowA >= n) rowA = n - 1;
  f32x4 acc1[8], acc2[8];
#pragma unroll
  for (int i = 0; i < 8; ++i) {
    acc1[i] = (f32x4){0.f, 0.f, 0.f, 0.f};
    acc2[i] = (f32x4){0.f, 0.f, 0.f, 0.f};
  }
  const float* ap = X + (size_t)rowA * 256 + q * 8;
#pragma unroll
  for (int kb = 0; kb < 8; ++kb) {
    bf16x8 a = load_a_f32(ap + kb * 32);
#pragma unroll
    for (int nt = 0; nt < 8; ++nt) {
      bf16x8 bv1 = *(const bf16x8*)(B1t + (nt * 16 + l15) * 256 + kb * 32 + q * 8);
      acc1[nt] = __builtin_amdgcn_mfma_f32_16x16x32_bf16(a, bv1, acc1[nt], 0, 0, 0);
      bf16x8 bv2 = *(const bf16x8*)(B2t + (nt * 16 + l15) * 256 + kb * 32 + q * 8);
      acc2[nt] = __builtin_amdgcn_mfma_f32_16x16x32_bf16(a, bv2, acc2[nt], 0, 0, 0);
    }
  }
  int rowBase = blockIdx.x * 64 + wave * 16 + q * 4;
#pragma unroll
  for (int nt = 0; nt < 8; ++nt) {
    int col = nt * 16 + l15;
    float bb = bias2[col];
#pragma unroll
    for (int r = 0; r < 4; ++r) {
      int row = rowBase + r;
      if (row < n) {
        O1[(size_t)row * 128 + col] = f2b(acc1[nt][r]);
        O2[(size_t)row * 128 + col] = acc2[nt][r] + bb;
      }
    }
  }
}

__global__ __launch_bounds__(256) void k_gemm_h_b16(
    const unsigned short* __restrict__ X, const unsigned short* __restrict__ Bt,
    unsigned short* __restrict__ O, int n) {
  int wave = threadIdx.x >> 6, lane = threadIdx.x & 63;
  int l15 = lane & 15, q = lane >> 4;
  int rowA = blockIdx.x * 64 + wave * 16 + l15;
  if (rowA >= n) rowA = n - 1;
  f32x4 acc[8];
#pragma unroll
  for (int i = 0; i < 8; ++i) acc[i] = (f32x4){0.f, 0.f, 0.f, 0.f};
  const unsigned short* ap = X + (size_t)rowA * 128 + q * 8;
#pragma unroll
  for (int kb = 0; kb < 4; ++kb) {
    bf16x8 a = *(const bf16x8*)(ap + kb * 32);
#pragma unroll
    for (int nt = 0; nt < 8; ++nt) {
      bf16x8 bv = *(const bf16x8*)(Bt + (nt * 16 + l15) * 128 + kb * 32 + q * 8);
      acc[nt] = __builtin_amdgcn_mfma_f32_16x16x32_bf16(a, bv, acc[nt], 0, 0, 0);
    }
  }
  int rowBase = blockIdx.x * 64 + wave * 16 + q * 4;
#pragma unroll
  for (int nt = 0; nt < 8; ++nt) {
    int col = nt * 16 + l15;
#pragma unroll
    for (int r = 0; r < 4; ++r) {
      int row = rowBase + r;
      if (row < n) O[(size_t)row * 128 + col] = f2b(acc[nt][r]);
    }
  }
}

__global__ __launch_bounds__(256) void k_gemm_h_f32(
    const unsigned short* __restrict__ X, const unsigned short* __restrict__ Bt,
    const float* __restrict__ bias, float* __restrict__ O, int n) {
  int wave = threadIdx.x >> 6, lane = threadIdx.x & 63;
  int l15 = lane & 15, q = lane >> 4;
  int rowA = blockIdx.x * 64 + wave * 16 + l15;
  if (rowA >= n) rowA = n - 1;
  f32x4 acc[8];
#pragma unroll
  for (int i = 0; i < 8; ++i) acc[i] = (f32x4){0.f, 0.f, 0.f, 0.f};
  const unsigned short* ap = X + (size_t)rowA * 128 + q * 8;
#pragma unroll
  for (int kb = 0; kb < 4; ++kb) {
    bf16x8 a = *(const bf16x8*)(ap + kb * 32);
#pragma unroll
    for (int nt = 0; nt < 8; ++nt) {
      bf16x8 bv = *(const bf16x8*)(Bt + (nt * 16 + l15) * 128 + kb * 32 + q * 8);
      acc[nt] = __builtin_amdgcn_mfma_f32_16x16x32_bf16(a, bv, acc[nt], 0, 0, 0);
    }
  }
  int rowBase = blockIdx.x * 64 + wave * 16 + q * 4;
#pragma unroll
  for (int nt = 0; nt < 8; ++nt) {
    int col = nt * 16 + l15;
    float bb = bias[col];
#pragma unroll
    for (int r = 0; r < 4; ++r) {
      int row = rowBase + r;
      if (row < n) O[(size_t)row * 128 + col] = acc[nt][r] + bb;
    }
  }
}

// ---------------- aggregation (wave per node, 2 feats/lane) ----------------
// Core loop: batch-load up to 64 edge indices + dinv coefs with one vector load
// each, broadcast per-edge via readlane, keep 4 row-gathers in flight.

__device__ __forceinline__ void agg_edges(
    const unsigned short* __restrict__ h, const int* __restrict__ csr_src,
    const float* __restrict__ dinv, int beg, int end, int lane,
    float& a0, float& a1) {
  for (int base = beg; base < end; base += 64) {
    int m = end - base; if (m > 64) m = 64;
    int ok = (base + lane < end);
    int idx_l = ok ? csr_src[base + lane] : 0;
    float c_l = ok ? dinv[idx_l] : 0.f;
    int j = 0;
    for (; j + 3 < m; j += 4) {
      int s0 = __builtin_amdgcn_readlane(idx_l, j);
      int s1 = __builtin_amdgcn_readlane(idx_l, j + 1);
      int s2 = __builtin_amdgcn_readlane(idx_l, j + 2);
      int s3 = __builtin_amdgcn_readlane(idx_l, j + 3);
      float c0 = rlf(c_l, j), c1 = rlf(c_l, j + 1);
      float c2 = rlf(c_l, j + 2), c3 = rlf(c_l, j + 3);
      unsigned int v0 = *(const unsigned int*)(h + (size_t)s0 * 128 + lane * 2);
      unsigned int v1 = *(const unsigned int*)(h + (size_t)s1 * 128 + lane * 2);
      unsigned int v2 = *(const unsigned int*)(h + (size_t)s2 * 128 + lane * 2);
      unsigned int v3 = *(const unsigned int*)(h + (size_t)s3 * 128 + lane * 2);
      a0 += c0 * b2f((unsigned short)v0); a1 += c0 * b2f((unsigned short)(v0 >> 16));
      a0 += c1 * b2f((unsigned short)v1); a1 += c1 * b2f((unsigned short)(v1 >> 16));
      a0 += c2 * b2f((unsigned short)v2); a1 += c2 * b2f((unsigned short)(v2 >> 16));
      a0 += c3 * b2f((unsigned short)v3); a1 += c3 * b2f((unsigned short)(v3 >> 16));
    }
    for (; j < m; ++j) {
      int s = __builtin_amdgcn_readlane(idx_l, j);
      float c = rlf(c_l, j);
      unsigned int v = *(const unsigned int*)(h + (size_t)s * 128 + lane * 2);
      a0 += c * b2f((unsigned short)v);
      a1 += c * b2f((unsigned short)(v >> 16));
    }
  }
}

__global__ __launch_bounds__(256) void k_agg1(
    const unsigned short* __restrict__ h,   // xW1 bf16 [n,128]
    const int* __restrict__ row_start, const int* __restrict__ csr_src,
    const float* __restrict__ dinv,
    const float* __restrict__ bias,         // b1
    unsigned short* __restrict__ hout, int n) {
  int gw = blockIdx.x * (blockDim.x >> 6) + (threadIdx.x >> 6);
  int lane = threadIdx.x & 63;
  if (gw >= n) return;
  int beg = row_start[gw], end = row_start[gw + 1];
  float dg = dinv[gw];
  float a0 = 0.f, a1 = 0.f;
  agg_edges(h, csr_src, dinv, beg, end, lane, a0, a1);
  a0 *= dg; a1 *= dg;  // coef = dinv[s]*dinv[gw]
  float sc = dg * dg;
  unsigned int v = *(const unsigned int*)(h + (size_t)gw * 128 + lane * 2);
  a0 += sc * b2f((unsigned short)v);
  a1 += sc * b2f((unsigned short)(v >> 16));
  a0 += bias[lane * 2];
  a1 += bias[lane * 2 + 1];
  a0 = fmaxf(a0, 0.f);
  a1 = fmaxf(a1, 0.f);
  unsigned int o = (unsigned int)f2b(a0) | ((unsigned int)f2b(a1) << 16);
  *(unsigned int*)(hout + (size_t)gw * 128 + lane * 2) = o;
}

// layer-2 aggregation + residual + b2 -> h; log_softmax (in place over residual),
// Wdeg head, bf16 h copy. res_out1 row gw: read-then-write by same wave only.
__global__ __launch_bounds__(256) void k_agg2_epi(
    const unsigned short* __restrict__ h,   // h1@W2 bf16 [n,128]
    const int* __restrict__ row_start, const int* __restrict__ csr_src,
    const float* __restrict__ dinv,
    const float* __restrict__ bias,    // b2
    float* res_out1,                   // in: x@Wd+bd; out: log_softmax
    const float* __restrict__ wdeg, const float* __restrict__ bdeg,
    float* __restrict__ out2,          // [n]
    unsigned short* __restrict__ hf,   // h bf16 [n,128]
    int n) {
  int gw = blockIdx.x * (blockDim.x >> 6) + (threadIdx.x >> 6);
  int lane = threadIdx.x & 63;
  if (gw >= n) return;
  int beg = row_start[gw], end = row_start[gw + 1];
  float dg = dinv[gw];
  float a0 = 0.f, a1 = 0.f;
  agg_edges(h, csr_src, dinv, beg, end, lane, a0, a1);
  a0 *= dg; a1 *= dg;
  float sc = dg * dg;
  unsigned int v = *(const unsigned int*)(h + (size_t)gw * 128 + lane * 2);
  a0 += sc * b2f((unsigned short)v);
  a1 += sc * b2f((unsigned short)(v >> 16));
  a0 += bias[lane * 2];
  a1 += bias[lane * 2 + 1];
  float2 rv = *(const float2*)(res_out1 + (size_t)gw * 128 + lane * 2);
  a0 += rv.x;
  a1 += rv.y;
  unsigned int o = (unsigned int)f2b(a0) | ((unsigned int)f2b(a1) << 16);
  *(unsigned int*)(hf + (size_t)gw * 128 + lane * 2) = o;
  // result2
  float t = a0 * wdeg[lane * 2] + a1 * wdeg[lane * 2 + 1];
#pragma unroll
  for (int m = 32; m >= 1; m >>= 1) t += __shfl_xor(t, m);
  if (lane == 0) out2[gw] = t + bdeg[0];
  // log_softmax
  float mx = fmaxf(a0, a1);
#pragma unroll
  for (int m = 32; m >= 1; m >>= 1) mx = fmaxf(mx, __shfl_xor(mx, m));
  float l = __expf(a0 - mx) + __expf(a1 - mx);
#pragma unroll
  for (int m = 32; m >= 1; m >>= 1) l += __shfl_xor(l, m);
  float ls = mx + __logf(l);
  float2 o1; o1.x = a0 - ls; o1.y = a1 - ls;
  *(float2*)(res_out1 + (size_t)gw * 128 + lane * 2) = o1;
}

// ---------------- launch ----------------

extern "C" void kernel_launch(void* const* d_in, const int* in_sizes, int n_in,
                              void* d_out, int out_size, void* d_ws, size_t ws_size,
                              hipStream_t stream) {
  const float* x   = (const float*)d_in[0];
  const int*   ei  = (const int*)d_in[1];
  const float* W1  = (const float*)d_in[2];
  const float* b1  = (const float*)d_in[3];
  const float* W2  = (const float*)d_in[4];
  const float* b2  = (const float*)d_in[5];
  const float* Wd  = (const float*)d_in[6];
  const float* bd  = (const float*)d_in[7];
  const float* Wdg = (const float*)d_in[8];
  const float* bdg = (const float*)d_in[9];
  const float* W3  = (const float*)d_in[10];
  const float* b3  = (const float*)d_in[11];

  const int N = in_sizes[0] / 256;
  const int E = in_sizes[1] / 2;

  // ---- workspace (~34 MB) ----
  char* w = (char*)d_ws;
  auto alloc = [&](size_t bytes) {
    char* p = w;
    w += (bytes + 255) & ~(size_t)255;
    return p;
  };
  unsigned short* W1t  = (unsigned short*)alloc((size_t)256 * 128 * 2);
  unsigned short* Wdt  = (unsigned short*)alloc((size_t)256 * 128 * 2);
  unsigned short* W2t  = (unsigned short*)alloc((size_t)128 * 128 * 2);
  unsigned short* W3t  = (unsigned short*)alloc((size_t)128 * 128 * 2);
  unsigned short* bufC = (unsigned short*)alloc((size_t)N * 128 * 2);  // h1/h bf16
  int*   deg      = (int*)alloc((size_t)N * 4);
  float* dinv     = (float*)alloc((size_t)N * 4);
  int*   row_start= (int*)alloc((size_t)(N + 1) * 4);
  int*   cursor   = (int*)alloc((size_t)N * 4);
  int*   partials = (int*)alloc(4096);
  int*   pprefix  = (int*)alloc(4096);
  int*   csr_src  = (int*)alloc((size_t)E * 4);

  // ---- d_out regions; out3 doubles as bf16 scratch bufA ----
  float* out1 = (float*)d_out;               // residual, then log_softmax
  float* out2 = out1 + (size_t)N * 128;
  float* out3 = out2 + (size_t)N;
  unsigned short* bufA = (unsigned short*)out3;  // xW1 / h1W2 bf16 (dead before out3)

  hipMemsetAsync(deg, 0, (size_t)N * 4, stream);

  k_wtrans4<<<CDIV(98304, 256), 256, 0, stream>>>(W1, Wd, W2, W3, W1t, Wdt, W2t, W3t);

  k_degcount<<<CDIV(E, 256), 256, 0, stream>>>(ei, E, deg);

  // fused x@W1 -> bufA (bf16), x@Wd+bd -> out1 (fp32 residual)
  k_gemm_x2<<<CDIV(N, 64), 256, 0, stream>>>(x, W1t, Wdt, bd, bufA, out1, N);

  const int nb = CDIV(N, 2048);
  k_scan1<<<nb, 256, 0, stream>>>(deg, row_start, partials, dinv, N);
  k_scan2<<<1, 64, 0, stream>>>(partials, pprefix, nb);
  k_scan3<<<CDIV(N, 256), 256, 0, stream>>>(pprefix, row_start, cursor, N, E);
  k_scatter<<<CDIV(E, 256), 256, 0, stream>>>(ei, E, cursor, csr_src);

  // layer 1: aggregate xW1, +b1, relu -> h1 (bufC)
  k_agg1<<<CDIV(N, 4), 256, 0, stream>>>(bufA, row_start, csr_src, dinv, b1, bufC, N);

  // h1 @ W2 -> bufA
  k_gemm_h_b16<<<CDIV(N, 64), 256, 0, stream>>>(bufC, W2t, bufA, N);

  // layer 2 aggregate + b2 + residual; log_softmax -> out1, deg head -> out2,
  // h bf16 -> bufC
  k_agg2_epi<<<CDIV(N, 4), 256, 0, stream>>>(bufA, row_start, csr_src, dinv,
                                             b2, out1, Wdg, bdg, out2, bufC, N);

  // result3 = h @ W3 + b3 -> out3
  k_gemm_h_f32<<<CDIV(N, 64), 256, 0, stream>>>(bufC, W3t, b3, out3, N);
}

// Round 5
// 680.477 us; speedup vs baseline: 1.3401x; 1.0398x over previous
//
#include <hip/hip_runtime.h>

// GNN_22505628631761: 2-layer GCN (sym-norm, self-loops) + residual + 3 outputs.
// fp32 in/out; bf16 MFMA GEMMs + bf16 h buffers internally.
// R5: GEMMs re-tiled to 64x64 per wave (block 128x128) after R4 showed
//     k_gemm_x2 latency-bound (MfmaUtil 3.6%, VALU 5%, occ 29%): old 16-row
//     wave tile issued 16 B-loads per 16 MFMAs (L1-thrashing). Now 12 loads
//     per 32 MFMAs + perm-based fp32->bf16 A conversion (3 ops/pair).

typedef __attribute__((ext_vector_type(8))) short bf16x8;
typedef __attribute__((ext_vector_type(4))) float f32x4;

#define CDIV(a, b) (((a) + (b) - 1) / (b))

__device__ __forceinline__ float b2f(unsigned short u) {
  union { unsigned int i; float f; } x; x.i = ((unsigned int)u) << 16; return x.f;
}
__device__ __forceinline__ unsigned short f2b(float f) {
  union { float f; unsigned int i; } x; x.f = f;
  unsigned int r = x.i + 0x7fffu + ((x.i >> 16) & 1u);  // RNE
  return (unsigned short)(r >> 16);
}
__device__ __forceinline__ float rlf(float v, int j) {
  union { float f; int i; } x; x.f = v;
  x.i = __builtin_amdgcn_readlane(x.i, j);
  return x.f;
}

// ---------------- setup kernels ----------------

// all four W [K][N] fp32 -> Wt [N][K] bf16 in one launch
__global__ void k_wtrans4(const float* __restrict__ W1, const float* __restrict__ Wd,
                          const float* __restrict__ W2, const float* __restrict__ W3,
                          unsigned short* __restrict__ W1t, unsigned short* __restrict__ Wdt,
                          unsigned short* __restrict__ W2t, unsigned short* __restrict__ W3t) {
  int idx = blockIdx.x * blockDim.x + threadIdx.x;
  const float* in; unsigned short* out; int K, N;
  if (idx < 32768)       { in = W1; out = W1t; K = 256; N = 128; }
  else if (idx < 65536)  { in = Wd; out = Wdt; K = 256; N = 128; idx -= 32768; }
  else if (idx < 81920)  { in = W2; out = W2t; K = 128; N = 128; idx -= 65536; }
  else if (idx < 98304)  { in = W3; out = W3t; K = 128; N = 128; idx -= 81920; }
  else return;
  int k = idx / N, n = idx - k * N;
  out[n * K + k] = f2b(in[idx]);
}

__global__ void k_degcount(const int* __restrict__ ei, int E, int* __restrict__ deg) {
  int e = blockIdx.x * blockDim.x + threadIdx.x;
  if (e >= E) return;
  atomicAdd(&deg[ei[E + e]], 1);
}

// exclusive scan over deg (2048/block) + dinv = rsqrt(deg+1)
__global__ void k_scan1(const int* __restrict__ deg, int* __restrict__ lscan,
                        int* __restrict__ partials, float* __restrict__ dinv, int n) {
  __shared__ int sd[256];
  int tid = threadIdx.x;
  int base = blockIdx.x * 2048 + tid * 8;
  int v[8]; int tsum = 0;
#pragma unroll
  for (int i = 0; i < 8; ++i) {
    int idx = base + i;
    int xv = (idx < n) ? deg[idx] : 0;
    v[i] = xv; tsum += xv;
    if (idx < n) dinv[idx] = 1.0f / sqrtf((float)xv + 1.0f);
  }
  sd[tid] = tsum;
  __syncthreads();
  for (int off = 1; off < 256; off <<= 1) {
    int t = (tid >= off) ? sd[tid - off] : 0;
    __syncthreads();
    sd[tid] += t;
    __syncthreads();
  }
  int run = sd[tid] - tsum;
#pragma unroll
  for (int i = 0; i < 8; ++i) {
    int idx = base + i;
    if (idx < n) lscan[idx] = run;
    run += v[i];
  }
  if (tid == 255) partials[blockIdx.x] = sd[255];
}

__global__ void k_scan2(const int* __restrict__ partials, int* __restrict__ pprefix, int nb) {
  if (threadIdx.x == 0 && blockIdx.x == 0) {
    int run = 0;
    for (int i = 0; i < nb; ++i) { pprefix[i] = run; run += partials[i]; }
    pprefix[nb] = run;
  }
}

__global__ void k_scan3(const int* __restrict__ pprefix, int* row_start,
                        int* __restrict__ cursor, int n, int E) {
  int idx = blockIdx.x * blockDim.x + threadIdx.x;
  if (idx >= n) return;
  int v = row_start[idx] + pprefix[idx >> 11];
  row_start[idx] = v;
  cursor[idx] = v;
  if (idx == 0) row_start[n] = E;
}

__global__ void k_scatter(const int* __restrict__ ei, int E, int* __restrict__ cursor,
                          int* __restrict__ csr_src) {
  int e = blockIdx.x * blockDim.x + threadIdx.x;
  if (e >= E) return;
  int s = ei[e], d = ei[E + e];
  int pos = atomicAdd(&cursor[d], 1);
  csr_src[pos] = s;
}

// ---------------- GEMMs (MFMA bf16 16x16x32) ----------------
// Block = 128 rows x 128 cols, 4 waves, each wave 64 rows x 64 cols (4x4 tiles).
// A frag lane: A[m=lane&15][k=(lane>>4)*8+j]; B frag from Bt[n][k] same addressing.
// C/D: col=lane&15, row=(lane>>4)*4+reg.

// 8 fp32 -> bf16x8 with round-half-up (+0x8000) and v_perm byte-pack.
__device__ __forceinline__ bf16x8 load_a_f32(const float* p) {
  const uint4* a4 = (const uint4*)p;
  uint4 lo = a4[0], hi = a4[1];
  union { bf16x8 v; unsigned int u[4]; } r;
  r.u[0] = __builtin_amdgcn_perm(lo.y + 0x8000u, lo.x + 0x8000u, 0x07060302u);
  r.u[1] = __builtin_amdgcn_perm(lo.w + 0x8000u, lo.z + 0x8000u, 0x07060302u);
  r.u[2] = __builtin_amdgcn_perm(hi.y + 0x8000u, hi.x + 0x8000u, 0x07060302u);
  r.u[3] = __builtin_amdgcn_perm(hi.w + 0x8000u, hi.z + 0x8000u, 0x07060302u);
  return r.v;
}

__global__ __launch_bounds__(256) void k_gemm_x2(
    const float* __restrict__ X,             // [n,256] fp32
    const unsigned short* __restrict__ B1t,  // [128,256] bf16 = W1^T
    const unsigned short* __restrict__ B2t,  // [128,256] bf16 = Wd^T
    const float* __restrict__ bias2,         // bd
    unsigned short* __restrict__ O1, float* __restrict__ O2, int n) {
  int wave = threadIdx.x >> 6, lane = threadIdx.x & 63;
  int l15 = lane & 15, q = lane >> 4;
  int wM = wave >> 1, wN = wave & 1;
  int rowBase = blockIdx.x * 128 + wM * 64;
  int colBase = wN * 64;
  f32x4 acc1[4][4], acc2[4][4];
#pragma unroll
  for (int i = 0; i < 4; ++i)
#pragma unroll
    for (int j = 0; j < 4; ++j) {
      acc1[i][j] = (f32x4){0.f, 0.f, 0.f, 0.f};
      acc2[i][j] = (f32x4){0.f, 0.f, 0.f, 0.f};
    }
  int rowIdx[4];
#pragma unroll
  for (int mt = 0; mt < 4; ++mt) {
    int r = rowBase + mt * 16 + l15;
    rowIdx[mt] = (r < n) ? r : (n - 1);
  }
#pragma unroll
  for (int kb = 0; kb < 8; ++kb) {
    bf16x8 a[4];
#pragma unroll
    for (int mt = 0; mt < 4; ++mt)
      a[mt] = load_a_f32(X + (size_t)rowIdx[mt] * 256 + kb * 32 + q * 8);
    bf16x8 b1[4], b2[4];
#pragma unroll
    for (int nt = 0; nt < 4; ++nt) {
      int col = colBase + nt * 16 + l15;
      b1[nt] = *(const bf16x8*)(B1t + (size_t)col * 256 + kb * 32 + q * 8);
      b2[nt] = *(const bf16x8*)(B2t + (size_t)col * 256 + kb * 32 + q * 8);
    }
#pragma unroll
    for (int mt = 0; mt < 4; ++mt)
#pragma unroll
      for (int nt = 0; nt < 4; ++nt) {
        acc1[mt][nt] = __builtin_amdgcn_mfma_f32_16x16x32_bf16(a[mt], b1[nt], acc1[mt][nt], 0, 0, 0);
        acc2[mt][nt] = __builtin_amdgcn_mfma_f32_16x16x32_bf16(a[mt], b2[nt], acc2[mt][nt], 0, 0, 0);
      }
  }
#pragma unroll
  for (int mt = 0; mt < 4; ++mt)
#pragma unroll
    for (int nt = 0; nt < 4; ++nt) {
      int col = colBase + nt * 16 + l15;
      float bb = bias2[col];
#pragma unroll
      for (int r = 0; r < 4; ++r) {
        int row = rowBase + mt * 16 + q * 4 + r;
        if (row < n) {
          O1[(size_t)row * 128 + col] = f2b(acc1[mt][nt][r]);
          O2[(size_t)row * 128 + col] = acc2[mt][nt][r] + bb;
        }
      }
    }
}

// A bf16 [n,128] @ Bt bf16 -> O bf16
__global__ __launch_bounds__(256) void k_gemm_h_b16(
    const unsigned short* __restrict__ X, const unsigned short* __restrict__ Bt,
    unsigned short* __restrict__ O, int n) {
  int wave = threadIdx.x >> 6, lane = threadIdx.x & 63;
  int l15 = lane & 15, q = lane >> 4;
  int wM = wave >> 1, wN = wave & 1;
  int rowBase = blockIdx.x * 128 + wM * 64;
  int colBase = wN * 64;
  f32x4 acc[4][4];
#pragma unroll
  for (int i = 0; i < 4; ++i)
#pragma unroll
    for (int j = 0; j < 4; ++j) acc[i][j] = (f32x4){0.f, 0.f, 0.f, 0.f};
  int rowIdx[4];
#pragma unroll
  for (int mt = 0; mt < 4; ++mt) {
    int r = rowBase + mt * 16 + l15;
    rowIdx[mt] = (r < n) ? r : (n - 1);
  }
#pragma unroll
  for (int kb = 0; kb < 4; ++kb) {
    bf16x8 a[4], b[4];
#pragma unroll
    for (int mt = 0; mt < 4; ++mt)
      a[mt] = *(const bf16x8*)(X + (size_t)rowIdx[mt] * 128 + kb * 32 + q * 8);
#pragma unroll
    for (int nt = 0; nt < 4; ++nt) {
      int col = colBase + nt * 16 + l15;
      b[nt] = *(const bf16x8*)(Bt + (size_t)col * 128 + kb * 32 + q * 8);
    }
#pragma unroll
    for (int mt = 0; mt < 4; ++mt)
#pragma unroll
      for (int nt = 0; nt < 4; ++nt)
        acc[mt][nt] = __builtin_amdgcn_mfma_f32_16x16x32_bf16(a[mt], b[nt], acc[mt][nt], 0, 0, 0);
  }
#pragma unroll
  for (int mt = 0; mt < 4; ++mt)
#pragma unroll
    for (int nt = 0; nt < 4; ++nt) {
      int col = colBase + nt * 16 + l15;
#pragma unroll
      for (int r = 0; r < 4; ++r) {
        int row = rowBase + mt * 16 + q * 4 + r;
        if (row < n) O[(size_t)row * 128 + col] = f2b(acc[mt][nt][r]);
      }
    }
}

// A bf16 [n,128] @ Bt bf16 + bias -> O fp32
__global__ __launch_bounds__(256) void k_gemm_h_f32(
    const unsigned short* __restrict__ X, const unsigned short* __restrict__ Bt,
    const float* __restrict__ bias, float* __restrict__ O, int n) {
  int wave = threadIdx.x >> 6, lane = threadIdx.x & 63;
  int l15 = lane & 15, q = lane >> 4;
  int wM = wave >> 1, wN = wave & 1;
  int rowBase = blockIdx.x * 128 + wM * 64;
  int colBase = wN * 64;
  f32x4 acc[4][4];
#pragma unroll
  for (int i = 0; i < 4; ++i)
#pragma unroll
    for (int j = 0; j < 4; ++j) acc[i][j] = (f32x4){0.f, 0.f, 0.f, 0.f};
  int rowIdx[4];
#pragma unroll
  for (int mt = 0; mt < 4; ++mt) {
    int r = rowBase + mt * 16 + l15;
    rowIdx[mt] = (r < n) ? r : (n - 1);
  }
#pragma unroll
  for (int kb = 0; kb < 4; ++kb) {
    bf16x8 a[4], b[4];
#pragma unroll
    for (int mt = 0; mt < 4; ++mt)
      a[mt] = *(const bf16x8*)(X + (size_t)rowIdx[mt] * 128 + kb * 32 + q * 8);
#pragma unroll
    for (int nt = 0; nt < 4; ++nt) {
      int col = colBase + nt * 16 + l15;
      b[nt] = *(const bf16x8*)(Bt + (size_t)col * 128 + kb * 32 + q * 8);
    }
#pragma unroll
    for (int mt = 0; mt < 4; ++mt)
#pragma unroll
      for (int nt = 0; nt < 4; ++nt)
        acc[mt][nt] = __builtin_amdgcn_mfma_f32_16x16x32_bf16(a[mt], b[nt], acc[mt][nt], 0, 0, 0);
  }
#pragma unroll
  for (int mt = 0; mt < 4; ++mt)
#pragma unroll
    for (int nt = 0; nt < 4; ++nt) {
      int col = colBase + nt * 16 + l15;
      float bb = bias[col];
#pragma unroll
      for (int r = 0; r < 4; ++r) {
        int row = rowBase + mt * 16 + q * 4 + r;
        if (row < n) O[(size_t)row * 128 + col] = acc[mt][nt][r] + bb;
      }
    }
}

// ---------------- aggregation (wave per node, 2 feats/lane) ----------------
// Batch-load 64 edge indices + dinv coefs per wave, readlane broadcast,
// 4 row-gathers in flight.

__device__ __forceinline__ void agg_edges(
    const unsigned short* __restrict__ h, const int* __restrict__ csr_src,
    const float* __restrict__ dinv, int beg, int end, int lane,
    float& a0, float& a1) {
  for (int base = beg; base < end; base += 64) {
    int m = end - base; if (m > 64) m = 64;
    int ok = (base + lane < end);
    int idx_l = ok ? csr_src[base + lane] : 0;
    float c_l = ok ? dinv[idx_l] : 0.f;
    int j = 0;
    for (; j + 3 < m; j += 4) {
      int s0 = __builtin_amdgcn_readlane(idx_l, j);
      int s1 = __builtin_amdgcn_readlane(idx_l, j + 1);
      int s2 = __builtin_amdgcn_readlane(idx_l, j + 2);
      int s3 = __builtin_amdgcn_readlane(idx_l, j + 3);
      float c0 = rlf(c_l, j), c1 = rlf(c_l, j + 1);
      float c2 = rlf(c_l, j + 2), c3 = rlf(c_l, j + 3);
      unsigned int v0 = *(const unsigned int*)(h + (size_t)s0 * 128 + lane * 2);
      unsigned int v1 = *(const unsigned int*)(h + (size_t)s1 * 128 + lane * 2);
      unsigned int v2 = *(const unsigned int*)(h + (size_t)s2 * 128 + lane * 2);
      unsigned int v3 = *(const unsigned int*)(h + (size_t)s3 * 128 + lane * 2);
      a0 += c0 * b2f((unsigned short)v0); a1 += c0 * b2f((unsigned short)(v0 >> 16));
      a0 += c1 * b2f((unsigned short)v1); a1 += c1 * b2f((unsigned short)(v1 >> 16));
      a0 += c2 * b2f((unsigned short)v2); a1 += c2 * b2f((unsigned short)(v2 >> 16));
      a0 += c3 * b2f((unsigned short)v3); a1 += c3 * b2f((unsigned short)(v3 >> 16));
    }
    for (; j < m; ++j) {
      int s = __builtin_amdgcn_readlane(idx_l, j);
      float c = rlf(c_l, j);
      unsigned int v = *(const unsigned int*)(h + (size_t)s * 128 + lane * 2);
      a0 += c * b2f((unsigned short)v);
      a1 += c * b2f((unsigned short)(v >> 16));
    }
  }
}

__global__ __launch_bounds__(256) void k_agg1(
    const unsigned short* __restrict__ h,   // xW1 bf16 [n,128]
    const int* __restrict__ row_start, const int* __restrict__ csr_src,
    const float* __restrict__ dinv,
    const float* __restrict__ bias,         // b1
    unsigned short* __restrict__ hout, int n) {
  int gw = blockIdx.x * (blockDim.x >> 6) + (threadIdx.x >> 6);
  int lane = threadIdx.x & 63;
  if (gw >= n) return;
  int beg = row_start[gw], end = row_start[gw + 1];
  float dg = dinv[gw];
  float a0 = 0.f, a1 = 0.f;
  agg_edges(h, csr_src, dinv, beg, end, lane, a0, a1);
  a0 *= dg; a1 *= dg;  // coef = dinv[s]*dinv[gw]
  float sc = dg * dg;
  unsigned int v = *(const unsigned int*)(h + (size_t)gw * 128 + lane * 2);
  a0 += sc * b2f((unsigned short)v);
  a1 += sc * b2f((unsigned short)(v >> 16));
  a0 += bias[lane * 2];
  a1 += bias[lane * 2 + 1];
  a0 = fmaxf(a0, 0.f);
  a1 = fmaxf(a1, 0.f);
  unsigned int o = (unsigned int)f2b(a0) | ((unsigned int)f2b(a1) << 16);
  *(unsigned int*)(hout + (size_t)gw * 128 + lane * 2) = o;
}

// layer-2 aggregation + residual + b2 -> h; log_softmax (in place over residual),
// Wdeg head, bf16 h copy. res_out1 row gw: read-then-write by same wave only.
__global__ __launch_bounds__(256) void k_agg2_epi(
    const unsigned short* __restrict__ h,   // h1@W2 bf16 [n,128]
    const int* __restrict__ row_start, const int* __restrict__ csr_src,
    const float* __restrict__ dinv,
    const float* __restrict__ bias,    // b2
    float* res_out1,                   // in: x@Wd+bd; out: log_softmax
    const float* __restrict__ wdeg, const float* __restrict__ bdeg,
    float* __restrict__ out2,          // [n]
    unsigned short* __restrict__ hf,   // h bf16 [n,128]
    int n) {
  int gw = blockIdx.x * (blockDim.x >> 6) + (threadIdx.x >> 6);
  int lane = threadIdx.x & 63;
  if (gw >= n) return;
  int beg = row_start[gw], end = row_start[gw + 1];
  float dg = dinv[gw];
  float a0 = 0.f, a1 = 0.f;
  agg_edges(h, csr_src, dinv, beg, end, lane, a0, a1);
  a0 *= dg; a1 *= dg;
  float sc = dg * dg;
  unsigned int v = *(const unsigned int*)(h + (size_t)gw * 128 + lane * 2);
  a0 += sc * b2f((unsigned short)v);
  a1 += sc * b2f((unsigned short)(v >> 16));
  a0 += bias[lane * 2];
  a1 += bias[lane * 2 + 1];
  float2 rv = *(const float2*)(res_out1 + (size_t)gw * 128 + lane * 2);
  a0 += rv.x;
  a1 += rv.y;
  unsigned int o = (unsigned int)f2b(a0) | ((unsigned int)f2b(a1) << 16);
  *(unsigned int*)(hf + (size_t)gw * 128 + lane * 2) = o;
  // result2
  float t = a0 * wdeg[lane * 2] + a1 * wdeg[lane * 2 + 1];
#pragma unroll
  for (int m = 32; m >= 1; m >>= 1) t += __shfl_xor(t, m);
  if (lane == 0) out2[gw] = t + bdeg[0];
  // log_softmax
  float mx = fmaxf(a0, a1);
#pragma unroll
  for (int m = 32; m >= 1; m >>= 1) mx = fmaxf(mx, __shfl_xor(mx, m));
  float l = __expf(a0 - mx) + __expf(a1 - mx);
#pragma unroll
  for (int m = 32; m >= 1; m >>= 1) l += __shfl_xor(l, m);
  float ls = mx + __logf(l);
  float2 o1; o1.x = a0 - ls; o1.y = a1 - ls;
  *(float2*)(res_out1 + (size_t)gw * 128 + lane * 2) = o1;
}

// ---------------- launch ----------------

extern "C" void kernel_launch(void* const* d_in, const int* in_sizes, int n_in,
                              void* d_out, int out_size, void* d_ws, size_t ws_size,
                              hipStream_t stream) {
  const float* x   = (const float*)d_in[0];
  const int*   ei  = (const int*)d_in[1];
  const float* W1  = (const float*)d_in[2];
  const float* b1  = (const float*)d_in[3];
  const float* W2  = (const float*)d_in[4];
  const float* b2  = (const float*)d_in[5];
  const float* Wd  = (const float*)d_in[6];
  const float* bd  = (const float*)d_in[7];
  const float* Wdg = (const float*)d_in[8];
  const float* bdg = (const float*)d_in[9];
  const float* W3  = (const float*)d_in[10];
  const float* b3  = (const float*)d_in[11];

  const int N = in_sizes[0] / 256;
  const int E = in_sizes[1] / 2;

  // ---- workspace (~34 MB) ----
  char* w = (char*)d_ws;
  auto alloc = [&](size_t bytes) {
    char* p = w;
    w += (bytes + 255) & ~(size_t)255;
    return p;
  };
  unsigned short* W1t  = (unsigned short*)alloc((size_t)256 * 128 * 2);
  unsigned short* Wdt  = (unsigned short*)alloc((size_t)256 * 128 * 2);
  unsigned short* W2t  = (unsigned short*)alloc((size_t)128 * 128 * 2);
  unsigned short* W3t  = (unsigned short*)alloc((size_t)128 * 128 * 2);
  unsigned short* bufC = (unsigned short*)alloc((size_t)N * 128 * 2);  // h1/h bf16
  int*   deg      = (int*)alloc((size_t)N * 4);
  float* dinv     = (float*)alloc((size_t)N * 4);
  int*   row_start= (int*)alloc((size_t)(N + 1) * 4);
  int*   cursor   = (int*)alloc((size_t)N * 4);
  int*   partials = (int*)alloc(4096);
  int*   pprefix  = (int*)alloc(4096);
  int*   csr_src  = (int*)alloc((size_t)E * 4);

  // ---- d_out regions; out3 doubles as bf16 scratch bufA ----
  float* out1 = (float*)d_out;               // residual, then log_softmax
  float* out2 = out1 + (size_t)N * 128;
  float* out3 = out2 + (size_t)N;
  unsigned short* bufA = (unsigned short*)out3;  // xW1 / h1W2 bf16 (dead before out3)

  hipMemsetAsync(deg, 0, (size_t)N * 4, stream);

  k_wtrans4<<<CDIV(98304, 256), 256, 0, stream>>>(W1, Wd, W2, W3, W1t, Wdt, W2t, W3t);

  k_degcount<<<CDIV(E, 256), 256, 0, stream>>>(ei, E, deg);

  // fused x@W1 -> bufA (bf16), x@Wd+bd -> out1 (fp32 residual)
  k_gemm_x2<<<CDIV(N, 128), 256, 0, stream>>>(x, W1t, Wdt, bd, bufA, out1, N);

  const int nb = CDIV(N, 2048);
  k_scan1<<<nb, 256, 0, stream>>>(deg, row_start, partials, dinv, N);
  k_scan2<<<1, 64, 0, stream>>>(partials, pprefix, nb);
  k_scan3<<<CDIV(N, 256), 256, 0, stream>>>(pprefix, row_start, cursor, N, E);
  k_scatter<<<CDIV(E, 256), 256, 0, stream>>>(ei, E, cursor, csr_src);

  // layer 1: aggregate xW1, +b1, relu -> h1 (bufC)
  k_agg1<<<CDIV(N, 4), 256, 0, stream>>>(bufA, row_start, csr_src, dinv, b1, bufC, N);

  // h1 @ W2 -> bufA
  k_gemm_h_b16<<<CDIV(N, 128), 256, 0, stream>>>(bufC, W2t, bufA, N);

  // layer 2 aggregate + b2 + residual; log_softmax -> out1, deg head -> out2,
  // h bf16 -> bufC
  k_agg2_epi<<<CDIV(N, 4), 256, 0, stream>>>(bufA, row_start, csr_src, dinv,
                                             b2, out1, Wdg, bdg, out2, bufC, N);

  // result3 = h @ W3 + b3 -> out3
  k_gemm_h_f32<<<CDIV(N, 128), 256, 0, stream>>>(bufC, W3t, b3, out3, N);
}